// Round 11
// baseline (203.072 us; speedup 1.0000x reference)
//
#include <hip/hip_runtime.h>
#include <math.h>

#define S_   4096
#define H_   8
#define D_   64
#define HD_  512
#define NCH  256   // chunks per batch
#define LCH  16    // seq steps per chunk
#define NCOL 2048  // scan columns = B * H * D

typedef __bf16 bf16x8 __attribute__((ext_vector_type(8)));
typedef float  f32x4  __attribute__((ext_vector_type(4)));

__device__ __forceinline__ float sigm(float v) { return 1.f / (1.f + __expf(-v)); }

// XOR-swizzled byte offset into a [rows][128] bf16 LDS tile (row stride 256B).
__device__ __forceinline__ int swzA(int row, int bytecol) {
  return row * 256 + (bytecol ^ ((row & 7) << 4));
}

// ---------------- K0: transpose weights to bf16 [n][k] ----------------
__global__ __launch_bounds__(256) void k_wt(const float* __restrict__ Wh,
                                            const float* __restrict__ Wo,
                                            __bf16* __restrict__ Wth,
                                            __bf16* __restrict__ Wto) {
  int idx = blockIdx.x * 256 + threadIdx.x;   // 0..32767
  if (idx < 24576) {
    int k = idx / 192, n = idx % 192;
    Wth[n * 128 + k] = (__bf16)Wh[idx];
  } else {
    int j = idx - 24576;                       // 0..8191, W_og[k][n], n<64
    int k = j >> 6, n = j & 63;
    Wto[n * 128 + k] = (__bf16)Wo[j];
  }
}

// ---------------- K1: per-chunk sums of x ----------------
__global__ __launch_bounds__(512) void k_chunk_sums(const float* __restrict__ x,
                                                    float* __restrict__ sums) {
  const int b = blockIdx.x >> 8, c = blockIdx.x & 255;
  const int t = threadIdx.x;
  const float* p = x + ((size_t)b * S_ + c * LCH) * HD_ + t;
  float acc = 0.f;
  #pragma unroll
  for (int i = 0; i < LCH; ++i) acc += p[(size_t)i * HD_];
  sums[((size_t)b * NCH + c) * HD_ + t] = acc;
}

// ---------------- 3-level exclusive scan of chunk sums (x offsets) -----------
__global__ __launch_bounds__(256) void kx_l1(const float* __restrict__ sums,
                                             float* __restrict__ gx) {
  int w = blockIdx.x * 256 + threadIdx.x;    // 0..32767
  int grp = w >> 11, col = w & 2047;
  int b = col >> 9, hd = col & 511;
  float s = 0.f;
  #pragma unroll
  for (int i = 0; i < 16; ++i)
    s += sums[((size_t)(b * NCH + grp * 16 + i)) * HD_ + hd];
  gx[grp * NCOL + col] = s;
}
__global__ __launch_bounds__(256) void kx_l2(float* __restrict__ gx) {
  int col = blockIdx.x * 256 + threadIdx.x;  // 0..2047
  float run = 0.f;
  #pragma unroll
  for (int g = 0; g < 16; ++g) {
    float v = gx[g * NCOL + col];
    gx[g * NCOL + col] = run;
    run += v;
  }
}
__global__ __launch_bounds__(256) void kx_l3(float* __restrict__ sums,
                                             const float* __restrict__ gx) {
  int w = blockIdx.x * 256 + threadIdx.x;
  int grp = w >> 11, col = w & 2047;
  int b = col >> 9, hd = col & 511;
  float run = gx[grp * NCOL + col];
  #pragma unroll
  for (int i = 0; i < 16; ++i) {
    size_t idx = ((size_t)(b * NCH + grp * 16 + i)) * HD_ + hd;
    float v = sums[idx];
    sums[idx] = run;
    run += v;
  }
}

// Stage weight fragments into LDS linearized by (ntile, ks, quad, l16):
// granule G holds W row n=ntile*16+l16, k-slot ks*32+quad*8. A wave's
// fragment read is then base + lane*16 (contiguous 1KB, conflict-free,
// compile-time ds offsets).
__device__ __forceinline__ void stage_w(const __bf16* __restrict__ Wg,
                                        char* Wl, int G) {
  int l16 = G & 15, quad = (G >> 4) & 3, ks = (G >> 6) & 3, ntile = G >> 8;
  int src = (ntile * 16 + l16) * 16 + ks * 4 + quad;
  ((bf16x8*)Wl)[G] = ((const bf16x8*)Wg)[src];
}

// -------- per-chunk body: LN -> LDS A-tile, 3-pass gates GEMM, chunk scan ----
// Runs on one 512-thread half (8 waves, wave = head). Weights read from LDS
// (linear fragment layout). LN is two-sweep: no run[17] array — sweep 1 keeps
// a scalar running prefix for the stats reduce, sweep 2 recomputes it from
// run0 (x re-loads are L2-hot). Identical fp32 arithmetic sequence.
// WRITE_TOT=true : write per-chunk scan totals cA/cB.
// WRITE_TOT=false: fused cell-emit (needs cin) -> bf16 cell into A-tile.
template <bool WRITE_TOT>
__device__ __forceinline__ void chunk_body(const float* __restrict__ x,
                                           const float* __restrict__ offs,
                                           const float* __restrict__ gamma,
                                           const float* __restrict__ beta,
                                           const float* __restrict__ bh,
                                           char* Alh, const char* WthL,
                                           float2 (*redW)[LCH],   // [8][16]
                                           float2* redF,          // [16]
                                           int cid,
                                           const float* __restrict__ cin,
                                           float* __restrict__ cA,
                                           float* __restrict__ cB) {
  const int t = threadIdx.x;
  const int th = t & 511;                 // column within chunk
  const int wave = (t >> 6) & 7;          // head
  const int lane = t & 63, quad = lane >> 4, l16 = lane & 15;
  const int b = cid >> 8, c = cid & 255;

  // ---- LN: column-parallel, two sweeps, one two-level reduction ----
  {
    const int dd = th & 63;
    const float* xp = x + ((size_t)b * S_ + c * LCH) * HD_ + th;
    const float run0 = offs[(size_t)cid * HD_ + th];
    float run = run0;
    #pragma unroll
    for (int s = 0; s < LCH; ++s) {
      float v = run, v2 = run * run;
      #pragma unroll
      for (int o = 32; o; o >>= 1) { v += __shfl_xor(v, o); v2 += __shfl_xor(v2, o); }
      if (lane == 0) redW[wave][s] = make_float2(v, v2);
      run += xp[(size_t)s * HD_];
    }
    __syncthreads();
    if (th < LCH) {
      float s1 = 0.f, s2 = 0.f;
      #pragma unroll
      for (int w = 0; w < 8; ++w) { float2 p = redW[w][th]; s1 += p.x; s2 += p.y; }
      float m = s1 * (1.f / HD_);
      float var = fmaf(-m, m, s2 * (1.f / HD_));
      redF[th] = make_float2(m, rsqrtf(var + 1e-5f));
    }
    __syncthreads();
    const float g = gamma[th], be = beta[th];
    run = run0;
    #pragma unroll
    for (int s = 0; s < LCH; ++s) {
      float2 st = redF[s];
      float lnv = (run - st.x) * st.y * g + be;
      float xv = xp[(size_t)s * HD_];
      int row = wave * 16 + s;
      *(__bf16*)(Alh + swzA(row, dd * 2)) = (__bf16)xv;
      *(__bf16*)(Alh + swzA(row, 128 + dd * 2)) = (__bf16)lnv;
      run += xv;
    }
  }
  // No barrier: A-tile rows [wave*16, wave*16+16) written/read by this wave.

  const int arow = wave * 16 + l16;
  float iv[16];
  // pass I (weight ntiles 0..3): iv = sigm(i)
  {
    f32x4 acc[4];
    #pragma unroll
    for (int nt = 0; nt < 4; ++nt) acc[nt] = (f32x4){0.f, 0.f, 0.f, 0.f};
    #pragma unroll
    for (int ks = 0; ks < 4; ++ks) {
      bf16x8 av = *(const bf16x8*)(Alh + swzA(arow, ks * 64 + quad * 16));
      #pragma unroll
      for (int nt = 0; nt < 4; ++nt) {
        bf16x8 bf_ = *(const bf16x8*)(WthL + ((nt * 4 + ks) * 64 + lane) * 16);
        acc[nt] = __builtin_amdgcn_mfma_f32_16x16x32_bf16(av, bf_, acc[nt], 0, 0, 0);
      }
    }
    #pragma unroll
    for (int nt = 0; nt < 4; ++nt) {
      float bi = bh[nt * 16 + l16];
      #pragma unroll
      for (int r = 0; r < 4; ++r) iv[nt * 4 + r] = sigm(acc[nt][r] + bi);
    }
  }
  // pass H (weight ntiles 8..11): iv *= relu(h)
  {
    f32x4 acc[4];
    #pragma unroll
    for (int nt = 0; nt < 4; ++nt) acc[nt] = (f32x4){0.f, 0.f, 0.f, 0.f};
    #pragma unroll
    for (int ks = 0; ks < 4; ++ks) {
      bf16x8 av = *(const bf16x8*)(Alh + swzA(arow, ks * 64 + quad * 16));
      #pragma unroll
      for (int nt = 0; nt < 4; ++nt) {
        bf16x8 bf_ = *(const bf16x8*)(WthL + (((8 + nt) * 4 + ks) * 64 + lane) * 16);
        acc[nt] = __builtin_amdgcn_mfma_f32_16x16x32_bf16(av, bf_, acc[nt], 0, 0, 0);
      }
    }
    #pragma unroll
    for (int nt = 0; nt < 4; ++nt) {
      float bh_ = bh[128 + nt * 16 + l16];
      #pragma unroll
      for (int r = 0; r < 4; ++r)
        iv[nt * 4 + r] = iv[nt * 4 + r] * fmaxf(acc[nt][r] + bh_, 0.f);
    }
  }
  // pass F (weight ntiles 4..7) + fused segmented affine scan per nt-group
  {
    f32x4 acc[4];
    #pragma unroll
    for (int nt = 0; nt < 4; ++nt) acc[nt] = (f32x4){0.f, 0.f, 0.f, 0.f};
    #pragma unroll
    for (int ks = 0; ks < 4; ++ks) {
      bf16x8 av = *(const bf16x8*)(Alh + swzA(arow, ks * 64 + quad * 16));
      #pragma unroll
      for (int nt = 0; nt < 4; ++nt) {
        bf16x8 bf_ = *(const bf16x8*)(WthL + (((4 + nt) * 4 + ks) * 64 + lane) * 16);
        acc[nt] = __builtin_amdgcn_mfma_f32_16x16x32_bf16(av, bf_, acc[nt], 0, 0, 0);
      }
    }
    #pragma unroll
    for (int nt = 0; nt < 4; ++nt) {
      float bf_ = bh[64 + nt * 16 + l16];
      float a = 1.f, bb2 = 0.f, pa[4], pb[4];
      #pragma unroll
      for (int r = 0; r < 4; ++r) {
        float fvv = sigm(acc[nt][r] + bf_);
        float gvv = iv[nt * 4 + r];
        a = fvv * a;
        bb2 = fmaf(fvv, bb2, gvv);
        pa[r] = a; pb[r] = bb2;
      }
      if constexpr (WRITE_TOT) {
        float TA = 1.f, TB = 0.f;
        #pragma unroll
        for (int q = 0; q < 4; ++q) {
          float Aq = __shfl(a, q * 16 + l16, 64);
          float Bq = __shfl(bb2, q * 16 + l16, 64);
          TB = fmaf(Aq, TB, Bq);
          TA = Aq * TA;
        }
        if (quad == 0) {
          cA[(size_t)cid * HD_ + wave * 64 + nt * 16 + l16] = TA;
          cB[(size_t)cid * HD_ + wave * 64 + nt * 16 + l16] = TB;
        }
      } else {
        float exA = 1.f, exB = 0.f;
        #pragma unroll
        for (int q = 0; q < 3; ++q) {
          float Aq = __shfl(a, q * 16 + l16, 64);
          float Bq = __shfl(bb2, q * 16 + l16, 64);
          if (q < quad) { exB = fmaf(Aq, exB, Bq); exA = Aq * exA; }
        }
        const int dcol = nt * 16 + l16;
        float ci = cin[(size_t)cid * HD_ + wave * 64 + dcol];
        float u = fmaf(exA, ci, exB);
        #pragma unroll
        for (int r = 0; r < 4; ++r) {
          float cv = fmaf(pa[r], u, pb[r]);
          int rowl = wave * 16 + quad * 4 + r;
          *(__bf16*)(Alh + swzA(rowl, 128 + dcol * 2)) = (__bf16)cv;
        }
      }
    }
  }
}

// ---------------- K4: persistent LN + gates GEMM + chunk scan -> cA/cB -------
// 256 blocks x 1024 threads: 2 chunk-lanes x 2 iterations = 4 chunks/block.
__global__ __launch_bounds__(1024)
__attribute__((amdgpu_waves_per_eu(4, 4)))
void k_gates_f(const float* __restrict__ x,
               const float* __restrict__ offs,
               const float* __restrict__ gamma,
               const float* __restrict__ beta,
               const __bf16* __restrict__ Wthg,
               const float* __restrict__ bh,
               float* __restrict__ cA,
               float* __restrict__ cB) {
  __shared__ char WthL[192 * 256];        // 48 KB, linear fragment layout
  __shared__ char Al[2][128 * 256];       // 2 x 32 KB A-tiles (swizzled)
  __shared__ float2 redW[2][8][LCH];
  __shared__ float2 redF[2][LCH];
  const int t = threadIdx.x;
  const int half = t >> 9;

  #pragma unroll
  for (int i = 0; i < 3; ++i) stage_w(Wthg, WthL, i * 1024 + t);
  __syncthreads();

  #pragma unroll 1
  for (int it = 0; it < 2; ++it) {
    const int cid = blockIdx.x * 4 + it * 2 + half;
    chunk_body<true>(x, offs, gamma, beta, bh, Al[half], WthL,
                     redW[half], redF[half], cid, nullptr, cA, cB);
  }
}

// ---------------- 3-level cross-chunk cell scan ------------------------------
__global__ __launch_bounds__(256) void kc_l1(const float* __restrict__ cA,
                                             const float* __restrict__ cB,
                                             float* __restrict__ gA,
                                             float* __restrict__ gB) {
  int w = blockIdx.x * 256 + threadIdx.x;
  int grp = w >> 11, col = w & 2047;
  int b = col >> 9, hd = col & 511;
  float Ag = 1.f, Bg = 0.f;
  #pragma unroll
  for (int i = 0; i < 16; ++i) {
    size_t idx = ((size_t)(b * NCH + grp * 16 + i)) * HD_ + hd;
    float Ac = cA[idx], Bc = cB[idx];
    Bg = fmaf(Ac, Bg, Bc);
    Ag = Ac * Ag;
  }
  gA[grp * NCOL + col] = Ag;
  gB[grp * NCOL + col] = Bg;
}
__global__ __launch_bounds__(256) void kc_l2(float* __restrict__ gA,
                                             const float* __restrict__ gB,
                                             const float* __restrict__ initcx) {
  int col = blockIdx.x * 256 + threadIdx.x;   // 0..2047
  int hd = col & 511;
  float run = initcx[hd];
  #pragma unroll
  for (int g = 0; g < 16; ++g) {
    float Ag = gA[g * NCOL + col], Bg = gB[g * NCOL + col];
    gA[g * NCOL + col] = run;                 // group run-in value
    run = fmaf(Ag, run, Bg);
  }
}
__global__ __launch_bounds__(256) void kc_l3(const float* __restrict__ cA,
                                             const float* __restrict__ cB,
                                             const float* __restrict__ gA,
                                             float* __restrict__ cin) {
  int w = blockIdx.x * 256 + threadIdx.x;
  int grp = w >> 11, col = w & 2047;
  int b = col >> 9, hd = col & 511;
  float run = gA[grp * NCOL + col];
  #pragma unroll
  for (int i = 0; i < 16; ++i) {
    size_t idx = ((size_t)(b * NCH + grp * 16 + i)) * HD_ + hd;
    cin[idx] = run;
    run = fmaf(cA[idx], run, cB[idx]);
  }
}

// ---------------- K6: persistent recompute + cell emit + og GEMM + out -------
__global__ __launch_bounds__(1024)
__attribute__((amdgpu_waves_per_eu(4, 4)))
void k_og_f(const float* __restrict__ x,
            const float* __restrict__ offs,
            const float* __restrict__ gamma,
            const float* __restrict__ beta,
            const __bf16* __restrict__ Wthg,
            const __bf16* __restrict__ Wtog,
            const float* __restrict__ bh,
            const float* __restrict__ bo,
            const float* __restrict__ cin,
            float* __restrict__ out) {
  __shared__ char WthL[192 * 256];        // 48 KB
  __shared__ char WtoL[64 * 256];         // 16 KB
  __shared__ char Al[2][128 * 256];       // 64 KB
  __shared__ float2 redW[2][8][LCH];
  __shared__ float2 redF[2][LCH];
  const int t = threadIdx.x;
  const int half = t >> 9;
  const int wave = (t >> 6) & 7;
  const int lane = t & 63, quad = lane >> 4, l16 = lane & 15;

  #pragma unroll
  for (int i = 0; i < 3; ++i) stage_w(Wthg, WthL, i * 1024 + t);
  stage_w(Wtog, WtoL, t);
  __syncthreads();

  #pragma unroll 1
  for (int it = 0; it < 2; ++it) {
    const int cid = blockIdx.x * 4 + it * 2 + half;
    const int b = cid >> 8, c = cid & 255;
    chunk_body<false>(x, offs, gamma, beta, bh, Al[half], WthL,
                      redW[half], redF[half], cid, cin, nullptr, nullptr);
    // og GEMM: A = [x | cell], W = WtoL; out = sigm(og)*cell (wave-local rows)
    const int arow = wave * 16 + l16;
    f32x4 acc[4];
    #pragma unroll
    for (int nt = 0; nt < 4; ++nt) acc[nt] = (f32x4){0.f, 0.f, 0.f, 0.f};
    #pragma unroll
    for (int ks = 0; ks < 4; ++ks) {
      bf16x8 av = *(const bf16x8*)(Al[half] + swzA(arow, ks * 64 + quad * 16));
      #pragma unroll
      for (int nt = 0; nt < 4; ++nt) {
        bf16x8 bf_ = *(const bf16x8*)(WtoL + ((nt * 4 + ks) * 64 + lane) * 16);
        acc[nt] = __builtin_amdgcn_mfma_f32_16x16x32_bf16(av, bf_, acc[nt], 0, 0, 0);
      }
    }
    #pragma unroll
    for (int nt = 0; nt < 4; ++nt) {
      const int dcol = nt * 16 + l16;
      float bv = bo[dcol];
      #pragma unroll
      for (int r = 0; r < 4; ++r) {
        int rowl = wave * 16 + quad * 4 + r;
        int s = quad * 4 + r;
        float og = sigm(acc[nt][r] + bv);
        float cv = (float)*(const __bf16*)(Al[half] + swzA(rowl, 128 + dcol * 2));
        out[(((size_t)b * S_ + c * LCH + s) * H_ + wave) * D_ + dcol] = og * cv;
      }
    }
  }
}

extern "C" void kernel_launch(void* const* d_in, const int* in_sizes, int n_in,
                              void* d_out, int out_size, void* d_ws, size_t ws_size,
                              hipStream_t stream) {
  const float* x      = (const float*)d_in[0];
  const float* W_hid  = (const float*)d_in[1];
  const float* b_hid  = (const float*)d_in[2];
  const float* W_og   = (const float*)d_in[3];
  const float* b_og   = (const float*)d_in[4];
  const float* gamma  = (const float*)d_in[5];
  const float* beta   = (const float*)d_in[6];
  const float* initcx = (const float*)d_in[7];
  float* out = (float*)d_out;
  float* ws  = (float*)d_ws;

  // ws layout (floats):
  float*  buf0 = ws;                      // sums -> offs (in place)   524288
  float*  cA   = ws + 524288;             //                           524288
  float*  cB   = cA + 524288;             //                           524288
  float*  cin  = cB + 524288;             //                           524288
  float*  gx   = cin + 524288;            // x-offset group sums        32768
  float*  gA   = gx + 32768;              // cell group compose A       32768
  float*  gB   = gA + 32768;              // cell group compose B       32768
  __bf16* Wth  = (__bf16*)(gB + 32768);   // [192][128] bf16
  __bf16* Wto  = Wth + 24576;             // [64][128] bf16

  k_wt         <<<128,  256, 0, stream>>>(W_hid, W_og, Wth, Wto);
  k_chunk_sums <<<1024, 512, 0, stream>>>(x, buf0);
  kx_l1        <<<128,  256, 0, stream>>>(buf0, gx);
  kx_l2        <<<8,    256, 0, stream>>>(gx);
  kx_l3        <<<128,  256, 0, stream>>>(buf0, gx);
  k_gates_f    <<<256, 1024, 0, stream>>>(x, buf0, gamma, beta, Wth, b_hid, cA, cB);
  kc_l1        <<<128,  256, 0, stream>>>(cA, cB, gA, gB);
  kc_l2        <<<8,    256, 0, stream>>>(gA, gB, initcx);
  kc_l3        <<<128,  256, 0, stream>>>(cA, cB, gA, cin);
  k_og_f       <<<256, 1024, 0, stream>>>(x, buf0, gamma, beta, Wth, Wto,
                                          b_hid, b_og, cin, out);
}